// Round 2
// baseline (660.434 us; speedup 1.0000x reference)
//
#include <hip/hip_runtime.h>
#include <math.h>

#define B_   8
#define K_   8
#define L_   4096
#define D_   256    // K of GEMM1, N of GEMM2
#define H_   512    // N of GEMM1, K of GEMM2
#define S_   1024
#define M_   65536
#define MAXF 4096

typedef _Float16 half8  __attribute__((ext_vector_type(8)));
typedef float    floatx4 __attribute__((ext_vector_type(4)));

// ws layout (bytes):
#define WS_LIMIT   0                       // float[8]
#define WS_COUNTER 64                      // int
#define WS_FLAGS   128                     // int[MAXF]
#define WS_W1T     65536                   // fp16 [512][256] = 256KB
#define WS_W2T     (65536 + H_*D_*2)       // fp16 [256][512] = 256KB

// LDS geometry (element = _Float16). Row strides padded so fragment
// ds_read_b128 across 16 'lr' rows lands on distinct bank groups:
//   XA_LD=264 -> 528B = 132 words = 4 mod 32   (2 lanes/bank, free)
//   H1_LD=520 -> 1040B = 260 words = 4 mod 32  (2 lanes/bank, free)
//   BS_LD=40  -> 80B  = 20 words  = 20 mod 32  (2 lanes/bank, free)
#define XA_LD    264
#define H1_LD    520
#define BS_LD    40

// ---------------------------------------------------------------------------
// Prep: blocks 0..1023 convert W1->W1T fp16, W2->W2T fp16 (transposed);
// blocks 1024..1031 per-batch argmax (first occurrence); block 1032 zeros ctr.
// ---------------------------------------------------------------------------
__global__ __launch_bounds__(256) void prep_kernel(const float* __restrict__ et,
                                                   const float* __restrict__ W1,
                                                   const float* __restrict__ W2,
                                                   char* __restrict__ ws) {
  __shared__ float sv[256];
  __shared__ int   si[256];
  const int blk = blockIdx.x;
  const int t   = threadIdx.x;
  if (blk < 1024) {
    int e = blk * 256 + t;               // 0..262143
    if (e < H_ * D_) {                   // W1T[n][k] = W1[k][n]
      int n = e >> 8, k = e & 255;
      ((_Float16*)(ws + WS_W1T))[e] = (_Float16)W1[(size_t)k * H_ + n];
    } else {
      int e2 = e - H_ * D_;              // W2T[n][k] = W2[k][n]
      int n = e2 >> 9, k = e2 & 511;
      ((_Float16*)(ws + WS_W2T))[e2] = (_Float16)W2[(size_t)k * D_ + n];
    }
  } else if (blk < 1032) {
    int b = blk - 1024;
    const float* row = et + (size_t)b * L_;
    float best = -INFINITY; int bidx = 0;
    for (int i = t; i < L_; i += 256) {
      float v = row[i];
      if (v > best) { best = v; bidx = i; }
    }
    sv[t] = best; si[t] = bidx;
    __syncthreads();
    for (int sft = 128; sft > 0; sft >>= 1) {
      if (t < sft) {
        float v2 = sv[t + sft]; int i2 = si[t + sft];
        if (v2 > sv[t] || (v2 == sv[t] && i2 < si[t])) { sv[t] = v2; si[t] = i2; }
      }
      __syncthreads();
    }
    if (t == 0) ((float*)(ws + WS_LIMIT))[b] = (float)si[0];
  } else {
    if (t == 0) *(int*)(ws + WS_COUNTER) = 0;
  }
}

// ---------------------------------------------------------------------------
// 32-row K-loop: A (32 rows fp16 in LDS) x B (256 rows streamed from
// L2-resident transposed weights) -> acc (wave tile 32x64, 1x4 waves).
// Single LDS B-buffer + register double-buffer (T14 async-split):
//   barrier -> issue next-step global loads -> frag reads + MFMA ->
//   barrier -> ds_write next tile.
// ---------------------------------------------------------------------------
__device__ __forceinline__ void run_gemm(
    const _Float16* __restrict__ Bglob, const int ldb, const int nsteps,
    const _Float16* __restrict__ Alds, const int lda,
    _Float16* __restrict__ Bs, const int t, floatx4 (&acc)[2][4])
{
  const int lane = t & 63, w = t >> 6;
  const int lr = lane & 15, quad = lane >> 4;
  const int coloff = w * 64;
  const int sr = lane >> 2, sk = lane & 3;
  const int srow0 = w * 64 + sr;          // + c*16 covers 256 rows

  uint4 breg[4];
  #pragma unroll
  for (int c = 0; c < 4; ++c)
    breg[c] = *(const uint4*)(Bglob + (size_t)(srow0 + c * 16) * ldb + sk * 8);
  #pragma unroll
  for (int c = 0; c < 4; ++c)
    *(uint4*)((char*)Bs + (srow0 + c * 16) * (BS_LD * 2) + sk * 16) = breg[c];

  for (int ks = 0; ks < nsteps; ++ks) {
    __syncthreads();                     // staged Bs (and caller's A) visible
    if (ks + 1 < nsteps) {               // issue next-step loads (no wait)
      const _Float16* src = Bglob + (ks + 1) * 32 + sk * 8;
      #pragma unroll
      for (int c = 0; c < 4; ++c)
        breg[c] = *(const uint4*)(src + (size_t)(srow0 + c * 16) * ldb);
    }
    half8 af[2], bf[4];
    #pragma unroll
    for (int mt = 0; mt < 2; ++mt)
      af[mt] = *(const half8*)(Alds + (mt * 16 + lr) * lda + ks * 32 + quad * 8);
    #pragma unroll
    for (int nt = 0; nt < 4; ++nt)
      bf[nt] = *(const half8*)(Bs + (coloff + nt * 16 + lr) * BS_LD + quad * 8);
    #pragma unroll
    for (int mt = 0; mt < 2; ++mt)
      #pragma unroll
      for (int nt = 0; nt < 4; ++nt)
        acc[mt][nt] = __builtin_amdgcn_mfma_f32_16x16x32_f16(af[mt], bf[nt], acc[mt][nt], 0, 0, 0);
    __syncthreads();                     // all reads of Bs done
    if (ks + 1 < nsteps) {               // overwrite Bs with next tile
      #pragma unroll
      for (int c = 0; c < 4; ++c)
        *(uint4*)((char*)Bs + (srow0 + c * 16) * (BS_LD * 2) + sk * 16) = breg[c];
    }
  }
}

// ---------------------------------------------------------------------------
// Fused: Xs->LDS; h1 = relu(Xs@W1+b1) kept in LDS; h2 = relu(h1@W2+b2);
// offset = h2@W3; pos/mask/flags; lerp gather -> out. No h1 HBM round trip.
// M=32 rows/block, 2048 blocks; ~70KB LDS -> 2 blocks/CU for phase overlap.
// ---------------------------------------------------------------------------
__global__ __launch_bounds__(256) void fused_kernel(
    const float* __restrict__ X, char* __restrict__ ws,
    const float* __restrict__ b1, const float* __restrict__ b2,
    const float* __restrict__ W3,
    float* __restrict__ out, float* __restrict__ maskv) {
  __shared__ __align__(16) _Float16 Xa[32 * XA_LD];     // 16.5 KB
  __shared__ __align__(16) _Float16 h1s[32 * H1_LD];    // 32.5 KB
  __shared__ __align__(16) _Float16 Bs[256 * BS_LD];    // 20.0 KB
  __shared__ float psum[4][32];
  __shared__ float posl[32];

  const _Float16* W1T    = (const _Float16*)(ws + WS_W1T);
  const _Float16* W2T    = (const _Float16*)(ws + WS_W2T);
  const float*    limitf = (const float*)(ws + WS_LIMIT);
  int*            counter = (int*)(ws + WS_COUNTER);
  int*            flags   = (int*)(ws + WS_FLAGS);

  const int t    = threadIdx.x;
  const int m0   = blockIdx.x * 32;     // 2048 blocks
  const int lane = t & 63, w = t >> 6;
  const int lr   = lane & 15, quad = lane >> 4;
  const int bk   = m0 >> 10;

  // ---- stage Xs (32 rows x 256 fp32 -> fp16 LDS) ----
  {
    const int r = t >> 3, q = t & 7;    // 32 rows x 8 col-chunks of 32
    const int s = (m0 + r) & 1023;
    const float* xrow = X + ((size_t)bk * L_ + 2 * s) * D_ + q * 32;
    _Float16* dst = Xa + r * XA_LD + q * 32;
    #pragma unroll
    for (int i = 0; i < 4; ++i) {
      float4 v0 = *(const float4*)(xrow + i * 8);
      float4 v1 = *(const float4*)(xrow + i * 8 + 4);
      half8 h;
      h[0]=(_Float16)v0.x; h[1]=(_Float16)v0.y; h[2]=(_Float16)v0.z; h[3]=(_Float16)v0.w;
      h[4]=(_Float16)v1.x; h[5]=(_Float16)v1.y; h[6]=(_Float16)v1.z; h[7]=(_Float16)v1.w;
      *(half8*)(dst + i * 8) = h;
    }
  }
  // (no explicit sync: run_gemm's loop-top barrier orders Xa writes
  //  before any fragment read)

  floatx4 acc[2][4];

  // ---- GEMM1: M=32 N=512 K=256, two N-halves of 256 ----
  #pragma unroll
  for (int nh = 0; nh < 2; ++nh) {
    #pragma unroll
    for (int mt = 0; mt < 2; ++mt)
      #pragma unroll
      for (int nt = 0; nt < 4; ++nt)
        acc[mt][nt] = (floatx4){0.f, 0.f, 0.f, 0.f};
    run_gemm(W1T + (size_t)nh * 256 * D_, D_, 8, Xa, XA_LD, Bs, t, acc);
    // epilogue: relu(acc+b1) -> h1s (LDS, padded layout)
    #pragma unroll
    for (int nt = 0; nt < 4; ++nt) {
      int col = nh * 256 + w * 64 + nt * 16 + lr;
      float bias = b1[col];
      #pragma unroll
      for (int mt = 0; mt < 2; ++mt) {
        int rowb = mt * 16 + quad * 4;
        #pragma unroll
        for (int rg = 0; rg < 4; ++rg) {
          float v = acc[mt][nt][rg] + bias;
          h1s[(rowb + rg) * H1_LD + col] = (_Float16)(v > 0.f ? v : 0.f);
        }
      }
    }
  }

  // ---- GEMM2: M=32 N=256 K=512, A fragments straight from h1s ----
  #pragma unroll
  for (int mt = 0; mt < 2; ++mt)
    #pragma unroll
    for (int nt = 0; nt < 4; ++nt)
      acc[mt][nt] = (floatx4){0.f, 0.f, 0.f, 0.f};
  run_gemm(W2T, H_, 16, h1s, H1_LD, Bs, t, acc);

  // ---- epilogue: relu + offset partials (fp32) ----
  float part[2][4] = {{0,0,0,0},{0,0,0,0}};
  #pragma unroll
  for (int nt = 0; nt < 4; ++nt) {
    int col = w * 64 + nt * 16 + lr;
    float bias = b2[col];
    float w3   = W3[col];
    #pragma unroll
    for (int mt = 0; mt < 2; ++mt)
      #pragma unroll
      for (int rg = 0; rg < 4; ++rg) {
        float h2 = acc[mt][nt][rg] + bias;
        h2 = h2 > 0.f ? h2 : 0.f;
        part[mt][rg] = fmaf(h2, w3, part[mt][rg]);
      }
  }
  #pragma unroll
  for (int mt = 0; mt < 2; ++mt)
    #pragma unroll
    for (int rg = 0; rg < 4; ++rg) {
      float p = part[mt][rg];
      p += __shfl_xor(p, 1, 64);
      p += __shfl_xor(p, 2, 64);
      p += __shfl_xor(p, 4, 64);
      p += __shfl_xor(p, 8, 64);
      if (lr == 0) psum[w][mt * 16 + quad * 4 + rg] = p;
    }
  __syncthreads();
  if (t < 32) {
    int   mrow  = m0 + t;
    float off   = psum[0][t] + psum[1][t] + psum[2][t] + psum[3][t];
    int   s     = mrow & 1023;
    float pos   = (float)(2 * s) + off;
    float limit = limitf[mrow >> 13];
    maskv[mrow] = (pos <= limit) ? 1.f : 0.f;
    posl[t] = pos;
    float d = pos - limit;
    if (d < 0.5f && d > -0.5f) {            // near-boundary -> exact fixup later
      int idx = atomicAdd(counter, 1);
      if (idx < MAXF) flags[idx] = mrow;
    }
  }
  __syncthreads();
  { // lerp gather -> out
    const int c4 = t & 63, rgp = t >> 6;
    const float* xbase = X + (size_t)bk * (L_ * D_);
    #pragma unroll 4
    for (int rr = 0; rr < 8; ++rr) {
      int   rI = rgp * 8 + rr;
      float p  = posl[rI];
      float x0f = floorf(p);
      float ww  = p - x0f;
      int i0 = (int)x0f, i1 = i0 + 1;
      float v0 = (i0 >= 0 && i0 < L_) ? (1.f - ww) : 0.f;
      float v1 = (i1 >= 0 && i1 < L_) ? ww : 0.f;
      int ic0 = min(max(i0, 0), L_ - 1), ic1 = min(max(i1, 0), L_ - 1);
      float4 g0 = *(const float4*)(xbase + (size_t)ic0 * D_ + c4 * 4);
      float4 g1 = *(const float4*)(xbase + (size_t)ic1 * D_ + c4 * 4);
      float4 o;
      o.x = v0 * g0.x + v1 * g1.x;
      o.y = v0 * g0.y + v1 * g1.y;
      o.z = v0 * g0.z + v1 * g1.z;
      o.w = v0 * g0.w + v1 * g1.w;
      *(float4*)(out + (size_t)(m0 + rI) * D_ + c4 * 4) = o;
    }
  }
}

// ---------------------------------------------------------------------------
// Fixup: exact fp32 recompute of offset for flagged near-boundary rows.
// ---------------------------------------------------------------------------
__global__ __launch_bounds__(256) void fixup_kernel(
    const float* __restrict__ X,  const float* __restrict__ W1,
    const float* __restrict__ b1, const float* __restrict__ W2,
    const float* __restrict__ b2, const float* __restrict__ W3,
    const char* __restrict__ ws, float* __restrict__ maskv) {
  __shared__ float xs[256];
  __shared__ float h1f[512];
  __shared__ float red[4];
  const float* limitf  = (const float*)(ws + WS_LIMIT);
  const int*   counter = (const int*)(ws + WS_COUNTER);
  const int*   flags   = (const int*)(ws + WS_FLAGS);
  const int t = threadIdx.x;
  const int cnt = min(*counter, MAXF);
  for (int fi = blockIdx.x; fi < cnt; fi += 64) {
    int mrow = flags[fi];
    int bk = mrow >> 10, s = mrow & 1023;
    const float* xrow = X + ((size_t)bk * L_ + 2 * s) * D_;
    xs[t] = xrow[t];
    __syncthreads();
    #pragma unroll
    for (int jj = 0; jj < 2; ++jj) {
      int j = t + jj * 256;
      float a = b1[j];
      for (int d = 0; d < 256; ++d)
        a = fmaf(xs[d], W1[(size_t)d * H_ + j], a);
      h1f[j] = a > 0.f ? a : 0.f;
    }
    __syncthreads();
    {
      float a = b2[t];
      for (int e = 0; e < 512; ++e)
        a = fmaf(h1f[e], W2[(size_t)e * D_ + t], a);
      float h2 = a > 0.f ? a : 0.f;
      float pp = h2 * W3[t];
      #pragma unroll
      for (int o = 32; o >= 1; o >>= 1) pp += __shfl_xor(pp, o, 64);
      if ((t & 63) == 0) red[t >> 6] = pp;
    }
    __syncthreads();
    if (t == 0) {
      float off   = red[0] + red[1] + red[2] + red[3];
      float pos   = (float)(2 * s) + off;
      float limit = limitf[mrow >> 13];
      maskv[mrow] = (pos <= limit) ? 1.f : 0.f;
    }
    __syncthreads();
  }
}

// ---------------------------------------------------------------------------
extern "C" void kernel_launch(void* const* d_in, const int* in_sizes, int n_in,
                              void* d_out, int out_size, void* d_ws, size_t ws_size,
                              hipStream_t stream) {
  const float* X  = (const float*)d_in[0];
  const float* et = (const float*)d_in[1];
  const float* W1 = (const float*)d_in[2];
  const float* b1 = (const float*)d_in[3];
  const float* W2 = (const float*)d_in[4];
  const float* b2 = (const float*)d_in[5];
  const float* W3 = (const float*)d_in[6];
  float* out   = (float*)d_out;
  float* maskv = out + (size_t)M_ * D_;
  char*  ws    = (char*)d_ws;

  prep_kernel <<<1033, 256, 0, stream>>>(et, W1, W2, ws);
  fused_kernel<<<2048, 256, 0, stream>>>(X, ws, b1, b2, W3, out, maskv);
  fixup_kernel<<<64,   256, 0, stream>>>(X, W1, b1, W2, b2, W3, ws, maskv);
}

// Round 3
// 460.089 us; speedup vs baseline: 1.4355x; 1.4355x over previous
//
#include <hip/hip_runtime.h>
#include <math.h>

#define B_   8
#define K_   8
#define L_   4096
#define D_   256    // K of GEMM1, N of GEMM2
#define H_   512    // N of GEMM1, K of GEMM2
#define S_   1024
#define M_   65536
#define MAXF 4096

typedef _Float16 half8  __attribute__((ext_vector_type(8)));
typedef float    floatx4 __attribute__((ext_vector_type(4)));

// ws layout (bytes):
#define WS_LIMIT   0                       // float[8]
#define WS_COUNTER 64                      // int
#define WS_FLAGS   128                     // int[MAXF]
// Fragment-tiled weights: W1f [32 ntile][8 ks][64 lane][8 halves] (256KB)
//                         W2f [16 ntile][16 ks][64 lane][8 halves] (256KB)
// lane l = (quad<<4)|lr holds  n = ntile*16 + (l&15), k = ks*32 + (l>>4)*8 + j
#define WS_W1F     65536
#define WS_W2F     (65536 + H_*D_*2)

// LDS row strides (halves), padded off power-of-2
#define XA_LD    264
#define H1_LD    520
#define KS1      8     // D_/32
#define KS2      16    // H_/32

// ---------------------------------------------------------------------------
// Prep: blocks 0..1023 build fragment-tiled fp16 W1f/W2f; blocks 1024..1031
// per-batch argmax (first occurrence); block 1032 zeros the fixup counter.
// ---------------------------------------------------------------------------
__global__ __launch_bounds__(256) void prep_kernel(const float* __restrict__ et,
                                                   const float* __restrict__ W1,
                                                   const float* __restrict__ W2,
                                                   char* __restrict__ ws) {
  __shared__ float sv[256];
  __shared__ int   si[256];
  const int blk = blockIdx.x;
  const int t   = threadIdx.x;
  if (blk < 1024) {
    int e = blk * 256 + t;               // 0..262143
    if (e < H_ * D_) {                   // W1f halves [0,131072)
      int tile = e >> 9, r = e & 511;
      int l = r >> 3, j = r & 7;
      int ntile = tile >> 3, ks = tile & 7;          // KS1 = 8
      int n = (ntile << 4) + (l & 15);
      int k = (ks << 5) + ((l >> 4) << 3) + j;
      ((_Float16*)(ws + WS_W1F))[e] = (_Float16)W1[(size_t)k * H_ + n];
    } else {
      int e2 = e - H_ * D_;              // W2f halves [0,131072)
      int tile = e2 >> 9, r = e2 & 511;
      int l = r >> 3, j = r & 7;
      int ntile = tile >> 4, ks = tile & 15;         // KS2 = 16
      int n = (ntile << 4) + (l & 15);
      int k = (ks << 5) + ((l >> 4) << 3) + j;
      ((_Float16*)(ws + WS_W2F))[e2] = (_Float16)W2[(size_t)k * D_ + n];
    }
  } else if (blk < 1032) {
    int b = blk - 1024;
    const float* row = et + (size_t)b * L_;
    float best = -INFINITY; int bidx = 0;
    for (int i = t; i < L_; i += 256) {
      float v = row[i];
      if (v > best) { best = v; bidx = i; }
    }
    sv[t] = best; si[t] = bidx;
    __syncthreads();
    for (int sft = 128; sft > 0; sft >>= 1) {
      if (t < sft) {
        float v2 = sv[t + sft]; int i2 = si[t + sft];
        if (v2 > sv[t] || (v2 == sv[t] && i2 < si[t])) { sv[t] = v2; si[t] = i2; }
      }
      __syncthreads();
    }
    if (t == 0) ((float*)(ws + WS_LIMIT))[b] = (float)si[0];
  } else {
    if (t == 0) *(int*)(ws + WS_COUNTER) = 0;
  }
}

// ---------------------------------------------------------------------------
// K-loop with B streamed L2 -> registers (no LDS, no barriers): depth-4
// rolling window of fragment loads (16 global_load_dwordx4 in flight,
// compiler emits counted vmcnt). A fragments from LDS (shared across waves).
// Wave tile 32x64: acc[2][4].
// ---------------------------------------------------------------------------
template<int KS>
__device__ __forceinline__ void gemm_l2b(
    const _Float16* __restrict__ Wf,     // + (wave ntile base)*KS*512 applied by caller
    const _Float16* __restrict__ Alds, const int lda,
    const int lane, floatx4 (&acc)[2][4])
{
  const int lr = lane & 15, quad = lane >> 4;
  const _Float16* wl = Wf + lane * 8;
  uint4 Bw[4][4];
  #pragma unroll
  for (int i = 0; i < 4; ++i)
    #pragma unroll
    for (int nt = 0; nt < 4; ++nt)
      Bw[i][nt] = *(const uint4*)(wl + ((size_t)nt * KS + i) * 512);
  #pragma unroll
  for (int ks = 0; ks < KS; ++ks) {
    half8 af0 = *(const half8*)(Alds + lr * lda + ks * 32 + quad * 8);
    half8 af1 = *(const half8*)(Alds + (16 + lr) * lda + ks * 32 + quad * 8);
    #pragma unroll
    for (int nt = 0; nt < 4; ++nt) {
      half8 bfv = *(const half8*)&Bw[ks & 3][nt];
      acc[0][nt] = __builtin_amdgcn_mfma_f32_16x16x32_f16(af0, bfv, acc[0][nt], 0, 0, 0);
      acc[1][nt] = __builtin_amdgcn_mfma_f32_16x16x32_f16(af1, bfv, acc[1][nt], 0, 0, 0);
    }
    if (ks + 4 < KS) {
      #pragma unroll
      for (int nt = 0; nt < 4; ++nt)
        Bw[ks & 3][nt] = *(const uint4*)(wl + ((size_t)nt * KS + ks + 4) * 512);
    }
  }
}

// ---------------------------------------------------------------------------
// Fused: Xs->LDS; h1 = relu(Xs@W1+b1) in LDS; h2 = relu(h1@W2+b2);
// offset = h2@W3; pos/mask/flags; lerp gather -> out.
// M=32/block, 2048 blocks, ~50KB LDS -> 3 blocks/CU; ~4 barriers total.
// ---------------------------------------------------------------------------
__global__ __launch_bounds__(256) void fused_kernel(
    const float* __restrict__ X, char* __restrict__ ws,
    const float* __restrict__ b1, const float* __restrict__ b2,
    const float* __restrict__ W3,
    float* __restrict__ out, float* __restrict__ maskv) {
  __shared__ __align__(16) _Float16 Xa[32 * XA_LD];     // 16.5 KB
  __shared__ __align__(16) _Float16 h1s[32 * H1_LD];    // 32.5 KB
  __shared__ float psum[4][32];
  __shared__ float posl[32];

  const _Float16* W1f    = (const _Float16*)(ws + WS_W1F);
  const _Float16* W2f    = (const _Float16*)(ws + WS_W2F);
  const float*    limitf = (const float*)(ws + WS_LIMIT);
  int*            counter = (int*)(ws + WS_COUNTER);
  int*            flags   = (int*)(ws + WS_FLAGS);

  const int t    = threadIdx.x;
  const int m0   = blockIdx.x * 32;     // 2048 blocks
  const int lane = t & 63, w = t >> 6;
  const int lr   = lane & 15, quad = lane >> 4;
  const int bk   = m0 >> 10;

  // ---- stage Xs (32 rows x 256 fp32 -> fp16 LDS) ----
  {
    const int r = t >> 3, q = t & 7;    // 32 rows x 8 col-chunks of 32
    const int s = (m0 + r) & 1023;
    const float* xrow = X + ((size_t)bk * L_ + 2 * s) * D_ + q * 32;
    _Float16* dst = Xa + r * XA_LD + q * 32;
    #pragma unroll
    for (int i = 0; i < 4; ++i) {
      float4 v0 = *(const float4*)(xrow + i * 8);
      float4 v1 = *(const float4*)(xrow + i * 8 + 4);
      half8 h;
      h[0]=(_Float16)v0.x; h[1]=(_Float16)v0.y; h[2]=(_Float16)v0.z; h[3]=(_Float16)v0.w;
      h[4]=(_Float16)v1.x; h[5]=(_Float16)v1.y; h[6]=(_Float16)v1.z; h[7]=(_Float16)v1.w;
      *(half8*)(dst + i * 8) = h;
    }
  }
  __syncthreads();

  floatx4 acc[2][4];

  // ---- GEMM1: M=32 N=512 K=256, two N-halves of 256; B from L2 ----
  #pragma unroll
  for (int nh = 0; nh < 2; ++nh) {
    #pragma unroll
    for (int mt = 0; mt < 2; ++mt)
      #pragma unroll
      for (int nt = 0; nt < 4; ++nt)
        acc[mt][nt] = (floatx4){0.f, 0.f, 0.f, 0.f};
    gemm_l2b<KS1>(W1f + (size_t)(nh * 16 + w * 4) * KS1 * 512, Xa, XA_LD, lane, acc);
    // epilogue: relu(acc+b1) -> h1s (LDS, padded layout)
    #pragma unroll
    for (int nt = 0; nt < 4; ++nt) {
      int col = nh * 256 + w * 64 + nt * 16 + lr;
      float bias = b1[col];
      #pragma unroll
      for (int mt = 0; mt < 2; ++mt) {
        int rowb = mt * 16 + quad * 4;
        #pragma unroll
        for (int rg = 0; rg < 4; ++rg) {
          float v = acc[mt][nt][rg] + bias;
          h1s[(rowb + rg) * H1_LD + col] = (_Float16)(v > 0.f ? v : 0.f);
        }
      }
    }
  }
  __syncthreads();   // h1s complete before GEMM2 fragment reads

  // ---- GEMM2: M=32 N=256 K=512; B from L2, A from h1s ----
  #pragma unroll
  for (int mt = 0; mt < 2; ++mt)
    #pragma unroll
    for (int nt = 0; nt < 4; ++nt)
      acc[mt][nt] = (floatx4){0.f, 0.f, 0.f, 0.f};
  gemm_l2b<KS2>(W2f + (size_t)(w * 4) * KS2 * 512, h1s, H1_LD, lane, acc);

  // ---- epilogue: relu + offset partials (fp32) ----
  float part[2][4] = {{0,0,0,0},{0,0,0,0}};
  #pragma unroll
  for (int nt = 0; nt < 4; ++nt) {
    int col = w * 64 + nt * 16 + lr;
    float bias = b2[col];
    float w3   = W3[col];
    #pragma unroll
    for (int mt = 0; mt < 2; ++mt)
      #pragma unroll
      for (int rg = 0; rg < 4; ++rg) {
        float h2 = acc[mt][nt][rg] + bias;
        h2 = h2 > 0.f ? h2 : 0.f;
        part[mt][rg] = fmaf(h2, w3, part[mt][rg]);
      }
  }
  #pragma unroll
  for (int mt = 0; mt < 2; ++mt)
    #pragma unroll
    for (int rg = 0; rg < 4; ++rg) {
      float p = part[mt][rg];
      p += __shfl_xor(p, 1, 64);
      p += __shfl_xor(p, 2, 64);
      p += __shfl_xor(p, 4, 64);
      p += __shfl_xor(p, 8, 64);
      if (lr == 0) psum[w][mt * 16 + quad * 4 + rg] = p;
    }
  __syncthreads();
  if (t < 32) {
    int   mrow  = m0 + t;
    float off   = psum[0][t] + psum[1][t] + psum[2][t] + psum[3][t];
    int   s     = mrow & 1023;
    float pos   = (float)(2 * s) + off;
    float limit = limitf[mrow >> 13];
    maskv[mrow] = (pos <= limit) ? 1.f : 0.f;
    posl[t] = pos;
    float d = pos - limit;
    if (d < 0.5f && d > -0.5f) {            // near-boundary -> exact fixup later
      int idx = atomicAdd(counter, 1);
      if (idx < MAXF) flags[idx] = mrow;
    }
  }
  __syncthreads();
  { // lerp gather -> out
    const int c4 = t & 63, rgp = t >> 6;
    const float* xbase = X + (size_t)bk * (L_ * D_);
    #pragma unroll 4
    for (int rr = 0; rr < 8; ++rr) {
      int   rI = rgp * 8 + rr;
      float p  = posl[rI];
      float x0f = floorf(p);
      float ww  = p - x0f;
      int i0 = (int)x0f, i1 = i0 + 1;
      float v0 = (i0 >= 0 && i0 < L_) ? (1.f - ww) : 0.f;
      float v1 = (i1 >= 0 && i1 < L_) ? ww : 0.f;
      int ic0 = min(max(i0, 0), L_ - 1), ic1 = min(max(i1, 0), L_ - 1);
      float4 g0 = *(const float4*)(xbase + (size_t)ic0 * D_ + c4 * 4);
      float4 g1 = *(const float4*)(xbase + (size_t)ic1 * D_ + c4 * 4);
      float4 o;
      o.x = v0 * g0.x + v1 * g1.x;
      o.y = v0 * g0.y + v1 * g1.y;
      o.z = v0 * g0.z + v1 * g1.z;
      o.w = v0 * g0.w + v1 * g1.w;
      *(float4*)(out + (size_t)(m0 + rI) * D_ + c4 * 4) = o;
    }
  }
}

// ---------------------------------------------------------------------------
// Fixup: exact fp32 recompute of offset for flagged near-boundary rows.
// ---------------------------------------------------------------------------
__global__ __launch_bounds__(256) void fixup_kernel(
    const float* __restrict__ X,  const float* __restrict__ W1,
    const float* __restrict__ b1, const float* __restrict__ W2,
    const float* __restrict__ b2, const float* __restrict__ W3,
    const char* __restrict__ ws, float* __restrict__ maskv) {
  __shared__ float xs[256];
  __shared__ float h1f[512];
  __shared__ float red[4];
  const float* limitf  = (const float*)(ws + WS_LIMIT);
  const int*   counter = (const int*)(ws + WS_COUNTER);
  const int*   flags   = (const int*)(ws + WS_FLAGS);
  const int t = threadIdx.x;
  const int cnt = min(*counter, MAXF);
  for (int fi = blockIdx.x; fi < cnt; fi += 64) {
    int mrow = flags[fi];
    int bk = mrow >> 10, s = mrow & 1023;
    const float* xrow = X + ((size_t)bk * L_ + 2 * s) * D_;
    xs[t] = xrow[t];
    __syncthreads();
    #pragma unroll
    for (int jj = 0; jj < 2; ++jj) {
      int j = t + jj * 256;
      float a = b1[j];
      for (int d = 0; d < 256; ++d)
        a = fmaf(xs[d], W1[(size_t)d * H_ + j], a);
      h1f[j] = a > 0.f ? a : 0.f;
    }
    __syncthreads();
    {
      float a = b2[t];
      for (int e = 0; e < 512; ++e)
        a = fmaf(h1f[e], W2[(size_t)e * D_ + t], a);
      float h2 = a > 0.f ? a : 0.f;
      float pp = h2 * W3[t];
      #pragma unroll
      for (int o = 32; o >= 1; o >>= 1) pp += __shfl_xor(pp, o, 64);
      if ((t & 63) == 0) red[t >> 6] = pp;
    }
    __syncthreads();
    if (t == 0) {
      float off   = red[0] + red[1] + red[2] + red[3];
      float pos   = (float)(2 * s) + off;
      float limit = limitf[mrow >> 13];
      maskv[mrow] = (pos <= limit) ? 1.f : 0.f;
    }
    __syncthreads();
  }
}

// ---------------------------------------------------------------------------
extern "C" void kernel_launch(void* const* d_in, const int* in_sizes, int n_in,
                              void* d_out, int out_size, void* d_ws, size_t ws_size,
                              hipStream_t stream) {
  const float* X  = (const float*)d_in[0];
  const float* et = (const float*)d_in[1];
  const float* W1 = (const float*)d_in[2];
  const float* b1 = (const float*)d_in[3];
  const float* W2 = (const float*)d_in[4];
  const float* b2 = (const float*)d_in[5];
  const float* W3 = (const float*)d_in[6];
  float* out   = (float*)d_out;
  float* maskv = out + (size_t)M_ * D_;
  char*  ws    = (char*)d_ws;

  prep_kernel <<<1033, 256, 0, stream>>>(et, W1, W2, ws);
  fused_kernel<<<2048, 256, 0, stream>>>(X, ws, b1, b2, W3, out, maskv);
  fixup_kernel<<<64,   256, 0, stream>>>(X, W1, b1, W2, b2, W3, ws, maskv);
}

// Round 4
// 434.226 us; speedup vs baseline: 1.5209x; 1.0596x over previous
//
#include <hip/hip_runtime.h>
#include <math.h>

#define B_   8
#define K_   8
#define L_   4096
#define D_   256    // K of GEMM1, N of GEMM2
#define H_   512    // N of GEMM1, K of GEMM2
#define S_   1024
#define M_   65536
#define MAXF 4096

typedef _Float16 half8  __attribute__((ext_vector_type(8)));
typedef float    floatx4 __attribute__((ext_vector_type(4)));

// ws layout (bytes):
#define WS_LIMIT   0                       // float[8]
#define WS_COUNTER 64                      // int
#define WS_FLAGS   128                     // int[MAXF]
// Fragment-tiled weights: W1f [32 ntile][8 ks][64 lane][8 halves] (256KB)
//                         W2f [16 ntile][16 ks][64 lane][8 halves] (256KB)
// lane l = (quad<<4)|lr holds  n = ntile*16 + (l&15), k = ks*32 + (l>>4)*8 + j
#define WS_W1F     65536
#define WS_W2F     (65536 + H_*D_*2)

// LDS row strides (halves), padded off power-of-2
#define XA_LD    264
#define H1_LD    520
#define KS1      8     // D_/32
#define KS2      16    // H_/32

// ---------------------------------------------------------------------------
// Prep: blocks 0..1023 build fragment-tiled fp16 W1f/W2f; blocks 1024..1031
// per-batch argmax (first occurrence); block 1032 zeros the fixup counter.
// ---------------------------------------------------------------------------
__global__ __launch_bounds__(256) void prep_kernel(const float* __restrict__ et,
                                                   const float* __restrict__ W1,
                                                   const float* __restrict__ W2,
                                                   char* __restrict__ ws) {
  __shared__ float sv[256];
  __shared__ int   si[256];
  const int blk = blockIdx.x;
  const int t   = threadIdx.x;
  if (blk < 1024) {
    int e = blk * 256 + t;               // 0..262143
    if (e < H_ * D_) {                   // W1f halves [0,131072)
      int tile = e >> 9, r = e & 511;
      int l = r >> 3, j = r & 7;
      int ntile = tile >> 3, ks = tile & 7;          // KS1 = 8
      int n = (ntile << 4) + (l & 15);
      int k = (ks << 5) + ((l >> 4) << 3) + j;
      ((_Float16*)(ws + WS_W1F))[e] = (_Float16)W1[(size_t)k * H_ + n];
    } else {
      int e2 = e - H_ * D_;              // W2f halves [0,131072)
      int tile = e2 >> 9, r = e2 & 511;
      int l = r >> 3, j = r & 7;
      int ntile = tile >> 4, ks = tile & 15;         // KS2 = 16
      int n = (ntile << 4) + (l & 15);
      int k = (ks << 5) + ((l >> 4) << 3) + j;
      ((_Float16*)(ws + WS_W2F))[e2] = (_Float16)W2[(size_t)k * D_ + n];
    }
  } else if (blk < 1032) {
    int b = blk - 1024;
    const float* row = et + (size_t)b * L_;
    float best = -INFINITY; int bidx = 0;
    for (int i = t; i < L_; i += 256) {
      float v = row[i];
      if (v > best) { best = v; bidx = i; }
    }
    sv[t] = best; si[t] = bidx;
    __syncthreads();
    for (int sft = 128; sft > 0; sft >>= 1) {
      if (t < sft) {
        float v2 = sv[t + sft]; int i2 = si[t + sft];
        if (v2 > sv[t] || (v2 == sv[t] && i2 < si[t])) { sv[t] = v2; si[t] = i2; }
      }
      __syncthreads();
    }
    if (t == 0) ((float*)(ws + WS_LIMIT))[b] = (float)si[0];
  } else {
    if (t == 0) *(int*)(ws + WS_COUNTER) = 0;
  }
}

// ---------------------------------------------------------------------------
// K-loop with B streamed L2 -> registers (no LDS, no barriers): depth-2
// rolling window (8 global_load_dwordx4 in flight -> counted vmcnt).
// A fragments from LDS. Wave tile 32x64: acc[2][4]. setprio(1) around the
// MFMA cluster (independent-block phase diversity regime).
// ---------------------------------------------------------------------------
template<int KS>
__device__ __forceinline__ void gemm_l2b(
    const _Float16* __restrict__ Wf,     // + (wave ntile base)*KS*512 by caller
    const _Float16* __restrict__ Alds, const int lda,
    const int lane, floatx4 (&acc)[2][4])
{
  const int lr = lane & 15, quad = lane >> 4;
  const _Float16* wl = Wf + lane * 8;
  uint4 Bw[2][4];
  #pragma unroll
  for (int i = 0; i < 2; ++i)
    #pragma unroll
    for (int nt = 0; nt < 4; ++nt)
      Bw[i][nt] = *(const uint4*)(wl + ((size_t)nt * KS + i) * 512);
  #pragma unroll
  for (int ks = 0; ks < KS; ++ks) {
    half8 af0 = *(const half8*)(Alds + lr * lda + ks * 32 + quad * 8);
    half8 af1 = *(const half8*)(Alds + (16 + lr) * lda + ks * 32 + quad * 8);
    __builtin_amdgcn_s_setprio(1);
    #pragma unroll
    for (int nt = 0; nt < 4; ++nt) {
      half8 bfv = *(const half8*)&Bw[ks & 1][nt];
      acc[0][nt] = __builtin_amdgcn_mfma_f32_16x16x32_f16(af0, bfv, acc[0][nt], 0, 0, 0);
      acc[1][nt] = __builtin_amdgcn_mfma_f32_16x16x32_f16(af1, bfv, acc[1][nt], 0, 0, 0);
    }
    __builtin_amdgcn_s_setprio(0);
    if (ks + 2 < KS) {                   // refill just-freed slot (WAR ok:
      #pragma unroll                     //  MFMA issued before the loads)
      for (int nt = 0; nt < 4; ++nt)
        Bw[ks & 1][nt] = *(const uint4*)(wl + ((size_t)nt * KS + ks + 2) * 512);
    }
  }
}

// ---------------------------------------------------------------------------
// Fused: Xa->LDS; GEMM1 both N-halves into regs (epilogue deferred so h1s
// can ALIAS Xa's LDS); h1 relu -> LDS; GEMM2; offset/pos/mask/flags; gather.
// ~34KB LDS + VGPR<=128 -> 4 blocks/CU. XCD-bijective swizzle: the 32 blocks
// sharing one 4MB X-slab co-reside on one XCD (slab L2-resident for gather).
// ---------------------------------------------------------------------------
__global__ __launch_bounds__(256, 4) void fused_kernel(
    const float* __restrict__ X, char* __restrict__ ws,
    const float* __restrict__ b1, const float* __restrict__ b2,
    const float* __restrict__ W3,
    float* __restrict__ out, float* __restrict__ maskv) {
  __shared__ __align__(16) _Float16 u[32 * H1_LD];   // 33.3KB: Xa then h1s
  __shared__ float psum[4][32];
  __shared__ float posl[32];
  _Float16* Xa  = u;                                  // stride XA_LD (16.5KB)
  _Float16* h1s = u;                                  // stride H1_LD (33.3KB)

  const _Float16* W1f    = (const _Float16*)(ws + WS_W1F);
  const _Float16* W2f    = (const _Float16*)(ws + WS_W2F);
  const float*    limitf = (const float*)(ws + WS_LIMIT);
  int*            counter = (int*)(ws + WS_COUNTER);
  int*            flags   = (int*)(ws + WS_FLAGS);

  const int t    = threadIdx.x;
  const int bid  = blockIdx.x;
  const int lt   = (bid & 7) * 256 + (bid >> 3);   // XCD-bijective (2048%8==0)
  const int m0   = lt * 32;
  const int lane = t & 63, w = t >> 6;
  const int lr   = lane & 15, quad = lane >> 4;
  const int bk   = m0 >> 10;

  // ---- stage Xa (32 rows x 256 fp32 -> fp16 LDS) ----
  {
    const int r = t >> 3, q = t & 7;    // 32 rows x 8 col-chunks of 32
    const int s = (m0 + r) & 1023;
    const float* xrow = X + ((size_t)bk * L_ + 2 * s) * D_ + q * 32;
    _Float16* dst = Xa + r * XA_LD + q * 32;
    #pragma unroll
    for (int i = 0; i < 4; ++i) {
      float4 v0 = *(const float4*)(xrow + i * 8);
      float4 v1 = *(const float4*)(xrow + i * 8 + 4);
      half8 h;
      h[0]=(_Float16)v0.x; h[1]=(_Float16)v0.y; h[2]=(_Float16)v0.z; h[3]=(_Float16)v0.w;
      h[4]=(_Float16)v1.x; h[5]=(_Float16)v1.y; h[6]=(_Float16)v1.z; h[7]=(_Float16)v1.w;
      *(half8*)(dst + i * 8) = h;
    }
  }
  __syncthreads();

  // ---- GEMM1: M=32 N=512 K=256, both N-halves, epilogue deferred ----
  floatx4 accA[2][4], accB[2][4];
  #pragma unroll
  for (int mt = 0; mt < 2; ++mt)
    #pragma unroll
    for (int nt = 0; nt < 4; ++nt) {
      accA[mt][nt] = (floatx4){0.f, 0.f, 0.f, 0.f};
      accB[mt][nt] = (floatx4){0.f, 0.f, 0.f, 0.f};
    }
  gemm_l2b<KS1>(W1f + (size_t)(w * 4) * KS1 * 512,        Xa, XA_LD, lane, accA);
  gemm_l2b<KS1>(W1f + (size_t)(16 + w * 4) * KS1 * 512,   Xa, XA_LD, lane, accB);
  __syncthreads();   // ALL Xa reads complete; h1s may now overwrite the union

  { // epilogue: relu(acc+b1) -> h1s (aliases Xa region; per-wave disjoint cols)
    auto epi = [&](floatx4 (&a)[2][4], int nh) {
      #pragma unroll
      for (int nt = 0; nt < 4; ++nt) {
        int col = nh * 256 + w * 64 + nt * 16 + lr;
        float bias = b1[col];
        #pragma unroll
        for (int mt = 0; mt < 2; ++mt) {
          int rowb = mt * 16 + quad * 4;
          #pragma unroll
          for (int rg = 0; rg < 4; ++rg) {
            float v = a[mt][nt][rg] + bias;
            h1s[(rowb + rg) * H1_LD + col] = (_Float16)(v > 0.f ? v : 0.f);
          }
        }
      }
    };
    epi(accA, 0);
    epi(accB, 1);
  }
  __syncthreads();   // h1s complete before GEMM2 fragment reads

  // ---- GEMM2: M=32 N=256 K=512; B from L2, A from h1s ----
  #pragma unroll
  for (int mt = 0; mt < 2; ++mt)
    #pragma unroll
    for (int nt = 0; nt < 4; ++nt)
      accA[mt][nt] = (floatx4){0.f, 0.f, 0.f, 0.f};
  gemm_l2b<KS2>(W2f + (size_t)(w * 4) * KS2 * 512, h1s, H1_LD, lane, accA);

  // ---- epilogue: relu + offset partials (fp32) ----
  float part[2][4] = {{0,0,0,0},{0,0,0,0}};
  #pragma unroll
  for (int nt = 0; nt < 4; ++nt) {
    int col = w * 64 + nt * 16 + lr;
    float bias = b2[col];
    float w3   = W3[col];
    #pragma unroll
    for (int mt = 0; mt < 2; ++mt)
      #pragma unroll
      for (int rg = 0; rg < 4; ++rg) {
        float h2 = accA[mt][nt][rg] + bias;
        h2 = h2 > 0.f ? h2 : 0.f;
        part[mt][rg] = fmaf(h2, w3, part[mt][rg]);
      }
  }
  #pragma unroll
  for (int mt = 0; mt < 2; ++mt)
    #pragma unroll
    for (int rg = 0; rg < 4; ++rg) {
      float p = part[mt][rg];
      p += __shfl_xor(p, 1, 64);
      p += __shfl_xor(p, 2, 64);
      p += __shfl_xor(p, 4, 64);
      p += __shfl_xor(p, 8, 64);
      if (lr == 0) psum[w][mt * 16 + quad * 4 + rg] = p;
    }
  __syncthreads();
  if (t < 32) {
    int   mrow  = m0 + t;
    float off   = psum[0][t] + psum[1][t] + psum[2][t] + psum[3][t];
    int   s     = mrow & 1023;
    float pos   = (float)(2 * s) + off;
    float limit = limitf[mrow >> 13];
    maskv[mrow] = (pos <= limit) ? 1.f : 0.f;
    posl[t] = pos;
    float d = pos - limit;
    if (d < 0.5f && d > -0.5f) {            // near-boundary -> exact fixup later
      int idx = atomicAdd(counter, 1);
      if (idx < MAXF) flags[idx] = mrow;
    }
  }
  __syncthreads();
  { // lerp gather -> out
    const int c4 = t & 63, rgp = t >> 6;
    const float* xbase = X + (size_t)bk * (L_ * D_);
    #pragma unroll 4
    for (int rr = 0; rr < 8; ++rr) {
      int   rI = rgp * 8 + rr;
      float p  = posl[rI];
      float x0f = floorf(p);
      float ww  = p - x0f;
      int i0 = (int)x0f, i1 = i0 + 1;
      float v0 = (i0 >= 0 && i0 < L_) ? (1.f - ww) : 0.f;
      float v1 = (i1 >= 0 && i1 < L_) ? ww : 0.f;
      int ic0 = min(max(i0, 0), L_ - 1), ic1 = min(max(i1, 0), L_ - 1);
      float4 g0 = *(const float4*)(xbase + (size_t)ic0 * D_ + c4 * 4);
      float4 g1 = *(const float4*)(xbase + (size_t)ic1 * D_ + c4 * 4);
      float4 o;
      o.x = v0 * g0.x + v1 * g1.x;
      o.y = v0 * g0.y + v1 * g1.y;
      o.z = v0 * g0.z + v1 * g1.z;
      o.w = v0 * g0.w + v1 * g1.w;
      *(float4*)(out + (size_t)(m0 + rI) * D_ + c4 * 4) = o;
    }
  }
}

// ---------------------------------------------------------------------------
// Fixup: exact fp32 recompute of offset for flagged near-boundary rows.
// ---------------------------------------------------------------------------
__global__ __launch_bounds__(256) void fixup_kernel(
    const float* __restrict__ X,  const float* __restrict__ W1,
    const float* __restrict__ b1, const float* __restrict__ W2,
    const float* __restrict__ b2, const float* __restrict__ W3,
    const char* __restrict__ ws, float* __restrict__ maskv) {
  __shared__ float xs[256];
  __shared__ float h1f[512];
  __shared__ float red[4];
  const float* limitf  = (const float*)(ws + WS_LIMIT);
  const int*   counter = (const int*)(ws + WS_COUNTER);
  const int*   flags   = (const int*)(ws + WS_FLAGS);
  const int t = threadIdx.x;
  const int cnt = min(*counter, MAXF);
  for (int fi = blockIdx.x; fi < cnt; fi += 64) {
    int mrow = flags[fi];
    int bk = mrow >> 10, s = mrow & 1023;
    const float* xrow = X + ((size_t)bk * L_ + 2 * s) * D_;
    xs[t] = xrow[t];
    __syncthreads();
    #pragma unroll
    for (int jj = 0; jj < 2; ++jj) {
      int j = t + jj * 256;
      float a = b1[j];
      for (int d = 0; d < 256; ++d)
        a = fmaf(xs[d], W1[(size_t)d * H_ + j], a);
      h1f[j] = a > 0.f ? a : 0.f;
    }
    __syncthreads();
    {
      float a = b2[t];
      for (int e = 0; e < 512; ++e)
        a = fmaf(h1f[e], W2[(size_t)e * D_ + t], a);
      float h2 = a > 0.f ? a : 0.f;
      float pp = h2 * W3[t];
      #pragma unroll
      for (int o = 32; o >= 1; o >>= 1) pp += __shfl_xor(pp, o, 64);
      if ((t & 63) == 0) red[t >> 6] = pp;
    }
    __syncthreads();
    if (t == 0) {
      float off   = red[0] + red[1] + red[2] + red[3];
      float pos   = (float)(2 * s) + off;
      float limit = limitf[mrow >> 13];
      maskv[mrow] = (pos <= limit) ? 1.f : 0.f;
    }
    __syncthreads();
  }
}

// ---------------------------------------------------------------------------
extern "C" void kernel_launch(void* const* d_in, const int* in_sizes, int n_in,
                              void* d_out, int out_size, void* d_ws, size_t ws_size,
                              hipStream_t stream) {
  const float* X  = (const float*)d_in[0];
  const float* et = (const float*)d_in[1];
  const float* W1 = (const float*)d_in[2];
  const float* b1 = (const float*)d_in[3];
  const float* W2 = (const float*)d_in[4];
  const float* b2 = (const float*)d_in[5];
  const float* W3 = (const float*)d_in[6];
  float* out   = (float*)d_out;
  float* maskv = out + (size_t)M_ * D_;
  char*  ws    = (char*)d_ws;

  prep_kernel <<<1033, 256, 0, stream>>>(et, W1, W2, ws);
  fused_kernel<<<2048, 256, 0, stream>>>(X, ws, b1, b2, W3, out, maskv);
  fixup_kernel<<<64,   256, 0, stream>>>(X, W1, b1, W2, b2, W3, ws, maskv);
}